// Round 10
// baseline (162.957 us; speedup 1.0000x reference)
//
#include <hip/hip_runtime.h>
#include <math.h>

// Capsule routing, fused. B=64, I=1024, O=1024 fp32.
//
// Math reduction: routing state collapses to c_k = softmax_o(u*w*vsum), so
// no [B,I,O] tensor is ever materialized.
//
// R7/R8/R9 lesson: global-global, LDS-LDS, and split-pipe stage_k all time
// the same -> no memory pipe is the limiter; still latency-bound. The
// common factor: waves_per_eu(4,4) pinned occupancy to 4 waves/SIMD with a
// 4-blocks/CU grid. R10: pure-global R7 structure (no LDS so occupancy
// isn't LDS-capped), amdgpu_waves_per_eu(8) (VGPR<=64, which this code
// already fits spill-free), IBLKS=128 -> 2048 blocks = 8 blocks/CU =
// 32 waves/CU full occupancy. 2x the wave-level latency hiding.

#define BB 64
#define II 1024
#define OO 1024
#define EPSF 1e-5f
#define LOG2E 1.44269504088896340736f

__device__ __forceinline__ float wave_sum(float v) {
    #pragma unroll
    for (int off = 32; off > 0; off >>= 1)
        v += __shfl_xor(v, off, 64);
    return v;
}
__device__ __forceinline__ float rfl(float x) {  // force SGPR broadcast
    return __int_as_float(__builtin_amdgcn_readfirstlane(__float_as_int(x)));
}

// ---------------- stage kernel ----------------
// grid = (BB/4) * IBLKS, block = 256. wave -> b = bg*4+wave.
// lane owns o = j*256 + lane*4 + e  (j,e in 0..3).
template<int IBLKS>
__global__ __launch_bounds__(256)
__attribute__((amdgpu_waves_per_eu(8)))
void stage_k(
    const float* __restrict__ u, const float* __restrict__ w,
    const float* __restrict__ v, float* __restrict__ part)
{
    constexpr int IPB = II / IBLKS;   // i's per block (= per wave)
    constexpr int NG  = IPB / 8;      // groups of 8 i's
    static_assert(IPB % 8 == 0, "need groups of 8");
    const int bg   = blockIdx.x / IBLKS;
    const int iblk = blockIdx.x % IBLKS;
    const int wave = threadIdx.x >> 6;
    const int lane = threadIdx.x & 63;
    const int b    = bg * 4 + wave;
    const float4* w4 = (const float4*)w;
    const float4* v4 = (const float4*)(v + b * OO);

    // v pre-scaled by log2e so logits feed v_exp_f32 directly.
    float vv[16];
    #pragma unroll
    for (int j = 0; j < 4; j++) {
        float4 a = v4[j * 64 + lane];
        vv[j*4+0]=a.x*LOG2E; vv[j*4+1]=a.y*LOG2E;
        vv[j*4+2]=a.z*LOG2E; vv[j*4+3]=a.w*LOG2E;
    }
    float ar[16];
    #pragma unroll
    for (int k = 0; k < 16; k++) ar[k] = 0.f;

    const int i0 = iblk * IPB;
    #pragma unroll 1
    for (int g = 0; g < NG; g++) {
        const int ib = i0 + g * 8;

        // u values -> SGPRs (wave-uniform loads)
        float us[8];
        #pragma unroll
        for (int ii = 0; ii < 8; ii++)
            us[ii] = rfl(u[b * II + ib + ii]);

        // ---- pass A: per-lane partial denominators (no cross-lane ops) ----
        float sA[8];
        #pragma unroll 2
        for (int ii = 0; ii < 8; ii++) {
            const int i = ib + ii;
            float a0;
            {
                float4 t = w4[i * 256 + 0 * 64 + lane];
                a0 = __builtin_amdgcn_exp2f((t.x * vv[0]) * us[ii])
                   + __builtin_amdgcn_exp2f((t.y * vv[1]) * us[ii])
                   + __builtin_amdgcn_exp2f((t.z * vv[2]) * us[ii])
                   + __builtin_amdgcn_exp2f((t.w * vv[3]) * us[ii]);
            }
            #pragma unroll
            for (int j = 1; j < 4; j++) {
                float4 t = w4[i * 256 + j * 64 + lane];
                a0 += __builtin_amdgcn_exp2f((t.x * vv[j*4+0]) * us[ii])
                    + __builtin_amdgcn_exp2f((t.y * vv[j*4+1]) * us[ii])
                    + __builtin_amdgcn_exp2f((t.z * vv[j*4+2]) * us[ii])
                    + __builtin_amdgcn_exp2f((t.w * vv[j*4+3]) * us[ii]);
            }
            sA[ii] = a0;
        }
        // ---- one batched butterfly: 6 layers x 8 independent chains ----
        #pragma unroll
        for (int off = 32; off > 0; off >>= 1) {
            #pragma unroll
            for (int ii = 0; ii < 8; ii++)
                sA[ii] += __shfl_xor(sA[ii], off, 64);
        }
        // q = u * rcp(denom) -> SGPRs
        float qs[8];
        #pragma unroll
        for (int ii = 0; ii < 8; ii++)
            qs[ii] = rfl(us[ii] * __builtin_amdgcn_rcpf(sA[ii]));

        // ---- pass B: re-stream (L1-hot, 32KB) w rows, accumulate ----
        #pragma unroll 2
        for (int ii = 0; ii < 8; ii++) {
            const int i = ib + ii;
            #pragma unroll
            for (int j = 0; j < 4; j++) {
                float4 t = w4[i * 256 + j * 64 + lane];
                float p;
                p = __builtin_amdgcn_exp2f((t.x * vv[j*4+0]) * us[ii]);
                ar[j*4+0] = fmaf(t.x * p, qs[ii], ar[j*4+0]);
                p = __builtin_amdgcn_exp2f((t.y * vv[j*4+1]) * us[ii]);
                ar[j*4+1] = fmaf(t.y * p, qs[ii], ar[j*4+1]);
                p = __builtin_amdgcn_exp2f((t.z * vv[j*4+2]) * us[ii]);
                ar[j*4+2] = fmaf(t.z * p, qs[ii], ar[j*4+2]);
                p = __builtin_amdgcn_exp2f((t.w * vv[j*4+3]) * us[ii]);
                ar[j*4+3] = fmaf(t.w * p, qs[ii], ar[j*4+3]);
            }
        }
    }
    // direct coalesced partial store: each wave owns its (b, iblk) slice
    float4* dst = (float4*)(part + ((size_t)iblk * BB + b) * OO);
    #pragma unroll
    for (int j = 0; j < 4; j++) {
        float4 o;
        o.x = ar[j*4+0]; o.y = ar[j*4+1]; o.z = ar[j*4+2]; o.w = ar[j*4+3];
        dst[j * 64 + lane] = o;
    }
}

// ---------------- partial GEMM (same block structure, single pass) -------
template<int IBLKS>
__global__ __launch_bounds__(256)
__attribute__((amdgpu_waves_per_eu(8)))
void gemm_k(
    const float* __restrict__ u, const float* __restrict__ w,
    float* __restrict__ part)
{
    constexpr int IPB = II / IBLKS;
    const int bg   = blockIdx.x / IBLKS;
    const int iblk = blockIdx.x % IBLKS;
    const int wave = threadIdx.x >> 6;
    const int lane = threadIdx.x & 63;
    const int b    = bg * 4 + wave;
    const float4* w4 = (const float4*)w;

    float ar[16];
    #pragma unroll
    for (int k = 0; k < 16; k++) ar[k] = 0.f;

    const int i0 = iblk * IPB;
    #pragma unroll 2
    for (int ii = 0; ii < IPB; ii++) {
        const int i = i0 + ii;
        const float ub = rfl(u[b * II + i]);
        #pragma unroll
        for (int j = 0; j < 4; j++) {
            float4 t = w4[i * 256 + j * 64 + lane];
            ar[j*4+0] = fmaf(ub, t.x, ar[j*4+0]);
            ar[j*4+1] = fmaf(ub, t.y, ar[j*4+1]);
            ar[j*4+2] = fmaf(ub, t.z, ar[j*4+2]);
            ar[j*4+3] = fmaf(ub, t.w, ar[j*4+3]);
        }
    }
    float4* dst = (float4*)(part + ((size_t)iblk * BB + b) * OO);
    #pragma unroll
    for (int j = 0; j < 4; j++) {
        float4 o;
        o.x = ar[j*4+0]; o.y = ar[j*4+1]; o.z = ar[j*4+2]; o.w = ar[j*4+3];
        dst[j * 64 + lane] = o;
    }
}

// ---------------- reduce + squash ----------------
// 1024 threads: thread (sl = t>>8, qd = t&255) sums slices
// [sl*nblk/4, (sl+1)*nblk/4) of o-quad qd; 16KB LDS float4 tree; squash
// epilogue on threads<256. mode 0: vbuf=v  1: vbuf+=v  2: out=v
__global__ __launch_bounds__(1024) void reduce_squash(
    const float* __restrict__ part, const float* __restrict__ bias,
    float* __restrict__ vbuf, float* __restrict__ out,
    float scale, int mode, int nblk)
{
    const int b  = blockIdx.x;
    const int t  = threadIdx.x;
    const int qd = t & 255;
    const int sl = t >> 8;
    const int per = nblk >> 2;
    const float4* p4 = (const float4*)part;

    float4 a0 = make_float4(0.f, 0.f, 0.f, 0.f), a1 = a0;
    const int k0 = sl * per;
    #pragma unroll 2
    for (int k = 0; k < per; k += 2) {
        float4 p0 = p4[(size_t)((k0 + k)     * BB + b) * 256 + qd];
        float4 p1 = p4[(size_t)((k0 + k + 1) * BB + b) * 256 + qd];
        a0.x += p0.x; a0.y += p0.y; a0.z += p0.z; a0.w += p0.w;
        a1.x += p1.x; a1.y += p1.y; a1.z += p1.z; a1.w += p1.w;
    }
    a0.x += a1.x; a0.y += a1.y; a0.z += a1.z; a0.w += a1.w;

    __shared__ float4 redq[1024];   // [sl][qd], 16 KB
    redq[t] = a0;
    __syncthreads();

    float ss = 0.f;
    float4 x;
    if (t < 256) {
        float4 r0 = redq[qd], r1 = redq[256 + qd],
               r2 = redq[512 + qd], r3 = redq[768 + qd];
        float4 s;
        s.x = (r0.x + r1.x) + (r2.x + r3.x);
        s.y = (r0.y + r1.y) + (r2.y + r3.y);
        s.z = (r0.z + r1.z) + (r2.z + r3.z);
        s.w = (r0.w + r1.w) + (r2.w + r3.w);
        float4 bb = ((const float4*)bias)[qd];
        x.x = fmaf(s.x, scale, bb.x); x.y = fmaf(s.y, scale, bb.y);
        x.z = fmaf(s.z, scale, bb.z); x.w = fmaf(s.w, scale, bb.w);
        ss = x.x*x.x + x.y*x.y + x.z*x.z + x.w*x.w;
    }
    ss = wave_sum(ss);              // waves 4..15 carry zeros
    __shared__ float red2[16];
    if ((t & 63) == 0) red2[t >> 6] = ss;
    __syncthreads();
    const float tot = (red2[0] + red2[1]) + (red2[2] + red2[3]);

    if (t < 256) {
        const float n = sqrtf(tot);
        const float f = tot / ((1.f + tot) * (n + EPSF));
        float4 vo;
        vo.x = x.x * f; vo.y = x.y * f; vo.z = x.z * f; vo.w = x.w * f;
        if (mode == 0) {
            ((float4*)(vbuf + b * OO))[qd] = vo;
        } else if (mode == 1) {
            float4 pv = ((const float4*)(vbuf + b * OO))[qd];
            pv.x += vo.x; pv.y += vo.y; pv.z += vo.z; pv.w += vo.w;
            ((float4*)(vbuf + b * OO))[qd] = pv;
        } else {
            ((float4*)(out + b * OO))[qd] = vo;
        }
    }
}

template<int IBLKS>
static void run_pipeline(const float* u, const float* w, const float* bias,
                         float* out, void* d_ws, hipStream_t stream)
{
    float* part = (float*)d_ws;
    float* vbuf = part + (size_t)IBLKS * BB * OO;
    dim3 g((BB / 4) * IBLKS), blk(256), rblk(1024);
    // v1 = squash((u@w)/O + bias)
    gemm_k<IBLKS><<<g, blk, 0, stream>>>(u, w, part);
    reduce_squash<<<dim3(BB), rblk, 0, stream>>>(part, bias, vbuf, out,
                                                 1.0f / (float)OO, 0, IBLKS);
    // vsum = v1 + squash(s2 + bias),  s2 via softmax(u*w*v1)
    stage_k<IBLKS><<<g, blk, 0, stream>>>(u, w, vbuf, part);
    reduce_squash<<<dim3(BB), rblk, 0, stream>>>(part, bias, vbuf, out,
                                                 1.0f, 1, IBLKS);
    // out = squash(s3 + bias),  s3 via softmax(u*w*vsum)
    stage_k<IBLKS><<<g, blk, 0, stream>>>(u, w, vbuf, part);
    reduce_squash<<<dim3(BB), rblk, 0, stream>>>(part, bias, vbuf, out,
                                                 1.0f, 2, IBLKS);
}

extern "C" void kernel_launch(void* const* d_in, const int* in_sizes, int n_in,
                              void* d_out, int out_size, void* d_ws, size_t ws_size,
                              hipStream_t stream) {
    (void)in_sizes; (void)n_in; (void)out_size;
    const float* u    = (const float*)d_in[0];
    const float* w    = (const float*)d_in[1];
    const float* bias = (const float*)d_in[2];
    float* out = (float*)d_out;

    const size_t row = (size_t)BB * OO * sizeof(float);  // 256 KB
    if      (ws_size >= 129 * row) run_pipeline<128>(u, w, bias, out, d_ws, stream);
    else if (ws_size >=  65 * row) run_pipeline<64>(u, w, bias, out, d_ws, stream);
    else if (ws_size >=  33 * row) run_pipeline<32>(u, w, bias, out, d_ws, stream);
    else                           run_pipeline<16>(u, w, bias, out, d_ws, stream);
}

// Round 11
// 157.975 us; speedup vs baseline: 1.0315x; 1.0315x over previous
//
#include <hip/hip_runtime.h>
#include <math.h>

// Capsule routing, fused. B=64, I=1024, O=1024 fp32.
//
// Math reduction: routing state collapses to c_k = softmax_o(u*w*vsum), so
// no [B,I,O] tensor is ever materialized.
//
// Allocator map (R2-R10): default launch_bounds(256) -> 64 VGPR;
// waves_per_eu(4,4) -> 64; waves_per_eu(8) -> 32 (!) + spill. So: don't
// force the allocator -- shrink the live set to fit 64 and raise TLP by
// grid shape. R11: o-SPLIT. Block = 4 waves = 2 b x 2 o-halves; each wave
// owns (b, 512 o's): vv[8]+ar[8]+sA[8] ~= 40 live VGPRs. Grid
// (BB/2)*IBLKS = 2048 blocks = 8 blocks/CU = 8 waves/SIMD (2x R7 TLP,
// which R7-R9 proved was the limiter; R10 proved spill kills the cheap
// way). Softmax denominator = own 512-o butterfly + partner wave's half
// via 8-float LDS exchange (double-buffered, 1 barrier/group).

#define BB 64
#define II 1024
#define OO 1024
#define EPSF 1e-5f
#define LOG2E 1.44269504088896340736f

__device__ __forceinline__ float wave_sum(float v) {
    #pragma unroll
    for (int off = 32; off > 0; off >>= 1)
        v += __shfl_xor(v, off, 64);
    return v;
}
__device__ __forceinline__ float rfl(float x) {  // force SGPR broadcast
    return __int_as_float(__builtin_amdgcn_readfirstlane(__float_as_int(x)));
}

// ---------------- stage kernel ----------------
// grid = (BB/2) * IBLKS, block = 256.
// wave -> b = bg*2 + (wave>>1), o-half oh = wave&1.
// lane owns o = (oh*2+j)*256 + lane*4 + e  (j in 0..1, e in 0..3).
template<int IBLKS>
__global__ __launch_bounds__(256) void stage_k(
    const float* __restrict__ u, const float* __restrict__ w,
    const float* __restrict__ v, float* __restrict__ part)
{
    constexpr int IPB = II / IBLKS;   // i's per block
    constexpr int NG  = IPB / 8;      // groups of 8 i's
    static_assert(IPB % 8 == 0, "need groups of 8");
    const int bg   = blockIdx.x / IBLKS;
    const int iblk = blockIdx.x % IBLKS;
    const int wave = threadIdx.x >> 6;
    const int lane = threadIdx.x & 63;
    const int b    = bg * 2 + (wave >> 1);
    const int oh   = wave & 1;
    const float4* w4 = (const float4*)w;
    const float4* v4 = (const float4*)(v + b * OO);

    // half-o denominator exchange: [buf][wave][ii]
    __shared__ float ex[2][4][8];

    // v pre-scaled by log2e so logits feed v_exp_f32 directly.
    float vv[8];
    #pragma unroll
    for (int j = 0; j < 2; j++) {
        float4 a = v4[oh * 128 + j * 64 + lane];
        vv[j*4+0]=a.x*LOG2E; vv[j*4+1]=a.y*LOG2E;
        vv[j*4+2]=a.z*LOG2E; vv[j*4+3]=a.w*LOG2E;
    }
    float ar[8];
    #pragma unroll
    for (int k = 0; k < 8; k++) ar[k] = 0.f;

    const int i0 = iblk * IPB;
    #pragma unroll 1
    for (int g = 0; g < NG; g++) {
        const int ib = i0 + g * 8;

        // u values -> SGPRs (wave-uniform loads)
        float us[8];
        #pragma unroll
        for (int ii = 0; ii < 8; ii++)
            us[ii] = rfl(u[b * II + ib + ii]);

        // ---- pass A: per-lane partial denominators over this o-half ----
        float sA[8];
        #pragma unroll 2
        for (int ii = 0; ii < 8; ii++) {
            const int i = ib + ii;
            float a0 = 0.f;
            #pragma unroll
            for (int j = 0; j < 2; j++) {
                float4 t = w4[i * 256 + oh * 128 + j * 64 + lane];
                a0 += __builtin_amdgcn_exp2f((t.x * vv[j*4+0]) * us[ii])
                    + __builtin_amdgcn_exp2f((t.y * vv[j*4+1]) * us[ii])
                    + __builtin_amdgcn_exp2f((t.z * vv[j*4+2]) * us[ii])
                    + __builtin_amdgcn_exp2f((t.w * vv[j*4+3]) * us[ii]);
            }
            sA[ii] = a0;
        }
        // ---- butterfly: 6 layers x 8 independent chains (512-o half) ----
        #pragma unroll
        for (int off = 32; off > 0; off >>= 1) {
            #pragma unroll
            for (int ii = 0; ii < 8; ii++)
                sA[ii] += __shfl_xor(sA[ii], off, 64);
        }
        // ---- exchange halves with partner wave (wave^1) via LDS ----
        if (lane == 0) {
            #pragma unroll
            for (int ii = 0; ii < 8; ii++)
                ex[g & 1][wave][ii] = sA[ii];
        }
        __syncthreads();
        // q = u * rcp(full denom) -> SGPRs
        float qs[8];
        #pragma unroll
        for (int ii = 0; ii < 8; ii++) {
            const float d = sA[ii] + ex[g & 1][wave ^ 1][ii];
            qs[ii] = rfl(us[ii] * __builtin_amdgcn_rcpf(d));
        }

        // ---- pass B: re-stream (L1-hot) w half-rows, accumulate ----
        #pragma unroll 2
        for (int ii = 0; ii < 8; ii++) {
            const int i = ib + ii;
            #pragma unroll
            for (int j = 0; j < 2; j++) {
                float4 t = w4[i * 256 + oh * 128 + j * 64 + lane];
                float p;
                p = __builtin_amdgcn_exp2f((t.x * vv[j*4+0]) * us[ii]);
                ar[j*4+0] = fmaf(t.x * p, qs[ii], ar[j*4+0]);
                p = __builtin_amdgcn_exp2f((t.y * vv[j*4+1]) * us[ii]);
                ar[j*4+1] = fmaf(t.y * p, qs[ii], ar[j*4+1]);
                p = __builtin_amdgcn_exp2f((t.z * vv[j*4+2]) * us[ii]);
                ar[j*4+2] = fmaf(t.z * p, qs[ii], ar[j*4+2]);
                p = __builtin_amdgcn_exp2f((t.w * vv[j*4+3]) * us[ii]);
                ar[j*4+3] = fmaf(t.w * p, qs[ii], ar[j*4+3]);
            }
        }
    }
    // direct coalesced partial store: wave owns (b, iblk, o-half) slice
    float4* dst = (float4*)(part + ((size_t)iblk * BB + b) * OO);
    #pragma unroll
    for (int j = 0; j < 2; j++) {
        float4 o;
        o.x = ar[j*4+0]; o.y = ar[j*4+1]; o.z = ar[j*4+2]; o.w = ar[j*4+3];
        dst[oh * 128 + j * 64 + lane] = o;
    }
}

// ---------------- partial GEMM (same o-split block structure) ----------
template<int IBLKS>
__global__ __launch_bounds__(256) void gemm_k(
    const float* __restrict__ u, const float* __restrict__ w,
    float* __restrict__ part)
{
    constexpr int IPB = II / IBLKS;
    const int bg   = blockIdx.x / IBLKS;
    const int iblk = blockIdx.x % IBLKS;
    const int wave = threadIdx.x >> 6;
    const int lane = threadIdx.x & 63;
    const int b    = bg * 2 + (wave >> 1);
    const int oh   = wave & 1;
    const float4* w4 = (const float4*)w;

    float ar[8];
    #pragma unroll
    for (int k = 0; k < 8; k++) ar[k] = 0.f;

    const int i0 = iblk * IPB;
    #pragma unroll 4
    for (int ii = 0; ii < IPB; ii++) {
        const int i = i0 + ii;
        const float ub = rfl(u[b * II + i]);
        #pragma unroll
        for (int j = 0; j < 2; j++) {
            float4 t = w4[i * 256 + oh * 128 + j * 64 + lane];
            ar[j*4+0] = fmaf(ub, t.x, ar[j*4+0]);
            ar[j*4+1] = fmaf(ub, t.y, ar[j*4+1]);
            ar[j*4+2] = fmaf(ub, t.z, ar[j*4+2]);
            ar[j*4+3] = fmaf(ub, t.w, ar[j*4+3]);
        }
    }
    float4* dst = (float4*)(part + ((size_t)iblk * BB + b) * OO);
    #pragma unroll
    for (int j = 0; j < 2; j++) {
        float4 o;
        o.x = ar[j*4+0]; o.y = ar[j*4+1]; o.z = ar[j*4+2]; o.w = ar[j*4+3];
        dst[oh * 128 + j * 64 + lane] = o;
    }
}

// ---------------- reduce + squash ----------------
// 1024 threads: thread (sl = t>>8, qd = t&255) sums slices
// [sl*nblk/4, (sl+1)*nblk/4) of o-quad qd; 16KB LDS float4 tree; squash
// epilogue on threads<256. mode 0: vbuf=v  1: vbuf+=v  2: out=v
__global__ __launch_bounds__(1024) void reduce_squash(
    const float* __restrict__ part, const float* __restrict__ bias,
    float* __restrict__ vbuf, float* __restrict__ out,
    float scale, int mode, int nblk)
{
    const int b  = blockIdx.x;
    const int t  = threadIdx.x;
    const int qd = t & 255;
    const int sl = t >> 8;
    const int per = nblk >> 2;
    const float4* p4 = (const float4*)part;

    float4 a0 = make_float4(0.f, 0.f, 0.f, 0.f), a1 = a0;
    const int k0 = sl * per;
    #pragma unroll 2
    for (int k = 0; k < per; k += 2) {
        float4 p0 = p4[(size_t)((k0 + k)     * BB + b) * 256 + qd];
        float4 p1 = p4[(size_t)((k0 + k + 1) * BB + b) * 256 + qd];
        a0.x += p0.x; a0.y += p0.y; a0.z += p0.z; a0.w += p0.w;
        a1.x += p1.x; a1.y += p1.y; a1.z += p1.z; a1.w += p1.w;
    }
    a0.x += a1.x; a0.y += a1.y; a0.z += a1.z; a0.w += a1.w;

    __shared__ float4 redq[1024];   // [sl][qd], 16 KB
    redq[t] = a0;
    __syncthreads();

    float ss = 0.f;
    float4 x;
    if (t < 256) {
        float4 r0 = redq[qd], r1 = redq[256 + qd],
               r2 = redq[512 + qd], r3 = redq[768 + qd];
        float4 s;
        s.x = (r0.x + r1.x) + (r2.x + r3.x);
        s.y = (r0.y + r1.y) + (r2.y + r3.y);
        s.z = (r0.z + r1.z) + (r2.z + r3.z);
        s.w = (r0.w + r1.w) + (r2.w + r3.w);
        float4 bb = ((const float4*)bias)[qd];
        x.x = fmaf(s.x, scale, bb.x); x.y = fmaf(s.y, scale, bb.y);
        x.z = fmaf(s.z, scale, bb.z); x.w = fmaf(s.w, scale, bb.w);
        ss = x.x*x.x + x.y*x.y + x.z*x.z + x.w*x.w;
    }
    ss = wave_sum(ss);              // waves 4..15 carry zeros
    __shared__ float red2[16];
    if ((t & 63) == 0) red2[t >> 6] = ss;
    __syncthreads();
    const float tot = (red2[0] + red2[1]) + (red2[2] + red2[3]);

    if (t < 256) {
        const float n = sqrtf(tot);
        const float f = tot / ((1.f + tot) * (n + EPSF));
        float4 vo;
        vo.x = x.x * f; vo.y = x.y * f; vo.z = x.z * f; vo.w = x.w * f;
        if (mode == 0) {
            ((float4*)(vbuf + b * OO))[qd] = vo;
        } else if (mode == 1) {
            float4 pv = ((const float4*)(vbuf + b * OO))[qd];
            pv.x += vo.x; pv.y += vo.y; pv.z += vo.z; pv.w += vo.w;
            ((float4*)(vbuf + b * OO))[qd] = pv;
        } else {
            ((float4*)(out + b * OO))[qd] = vo;
        }
    }
}

template<int IBLKS>
static void run_pipeline(const float* u, const float* w, const float* bias,
                         float* out, void* d_ws, hipStream_t stream)
{
    float* part = (float*)d_ws;
    float* vbuf = part + (size_t)IBLKS * BB * OO;
    dim3 g((BB / 2) * IBLKS), blk(256), rblk(1024);
    // v1 = squash((u@w)/O + bias)
    gemm_k<IBLKS><<<g, blk, 0, stream>>>(u, w, part);
    reduce_squash<<<dim3(BB), rblk, 0, stream>>>(part, bias, vbuf, out,
                                                 1.0f / (float)OO, 0, IBLKS);
    // vsum = v1 + squash(s2 + bias),  s2 via softmax(u*w*v1)
    stage_k<IBLKS><<<g, blk, 0, stream>>>(u, w, vbuf, part);
    reduce_squash<<<dim3(BB), rblk, 0, stream>>>(part, bias, vbuf, out,
                                                 1.0f, 1, IBLKS);
    // out = squash(s3 + bias),  s3 via softmax(u*w*vsum)
    stage_k<IBLKS><<<g, blk, 0, stream>>>(u, w, vbuf, part);
    reduce_squash<<<dim3(BB), rblk, 0, stream>>>(part, bias, vbuf, out,
                                                 1.0f, 2, IBLKS);
}

extern "C" void kernel_launch(void* const* d_in, const int* in_sizes, int n_in,
                              void* d_out, int out_size, void* d_ws, size_t ws_size,
                              hipStream_t stream) {
    (void)in_sizes; (void)n_in; (void)out_size;
    const float* u    = (const float*)d_in[0];
    const float* w    = (const float*)d_in[1];
    const float* bias = (const float*)d_in[2];
    float* out = (float*)d_out;

    const size_t row = (size_t)BB * OO * sizeof(float);  // 256 KB
    if      (ws_size >= 65 * row) run_pipeline<64>(u, w, bias, out, d_ws, stream);
    else if (ws_size >= 33 * row) run_pipeline<32>(u, w, bias, out, d_ws, stream);
    else if (ws_size >= 17 * row) run_pipeline<16>(u, w, bias, out, d_ws, stream);
    else                          run_pipeline<8>(u, w, bias, out, d_ws, stream);
}